// Round 4
// baseline (319.755 us; speedup 1.0000x reference)
//
#include <hip/hip_runtime.h>
#include <hip/hip_bf16.h>
#include <cstddef>

#define B_ 32
#define T_ 2048
#define D_ 512
#define U_ 512

typedef __attribute__((ext_vector_type(8))) short bf16x8;   // 8 bf16 = 4 VGPRs
typedef __attribute__((ext_vector_type(4))) float f32x4;    // MFMA 16x16 accum

__device__ __forceinline__ unsigned short f2bf(float f) {
  union { float f; unsigned u; } x; x.f = f;
  unsigned r = x.u + 0x7fffu + ((x.u >> 16) & 1u);  // RNE
  return (unsigned short)(r >> 16);
}
__device__ __forceinline__ unsigned pack2bf(float a, float b) {
  return (unsigned)f2bf(a) | ((unsigned)f2bf(b) << 16);
}
__device__ __forceinline__ float tanh_fast(float x) {
  // tanh(x) = 1 - 2/(e^{2x}+1); saturates correctly at +/-inf
  float e = __expf(2.0f * x);
  return 1.0f - 2.0f * __builtin_amdgcn_rcpf(e + 1.0f);
}

// ---------- k0: W2 [D][U] fp32 -> W2T [U][D] bf16 (B-operand friendly) ----------
__global__ void k0_w2t(const float* __restrict__ W2, unsigned short* __restrict__ W2T) {
  __shared__ float tile[32][65];            // [u][d], +1 pad
  const int d0 = blockIdx.x * 64, u0 = blockIdx.y * 32;
  const int tid = threadIdx.x;              // 256
  for (int i = tid; i < 64 * 32; i += 256) {
    int dl = i >> 5, ul = i & 31;           // consecutive tid -> consecutive u: coalesced
    tile[ul][dl] = W2[(size_t)(d0 + dl) * U_ + (u0 + ul)];
  }
  __syncthreads();
  for (int i = tid; i < 32 * 32; i += 256) {
    int ul = i >> 5, dp = i & 31;           // consecutive tid -> consecutive d-pair: coalesced
    unsigned p = pack2bf(tile[ul][2 * dp], tile[ul][2 * dp + 1]);
    ((unsigned*)W2T)[(size_t)(u0 + ul) * (D_ / 2) + (d0 >> 1) + dp] = p;
  }
}

// ---------- k1: q_proj (+ fold W1_b + W2_b) ; zero score & context ----------
__global__ void k1_qp(const float* __restrict__ query, const float* __restrict__ W1,
                      const float* __restrict__ W1b, const float* __restrict__ W2b,
                      float* __restrict__ qp, float* __restrict__ score,
                      float* __restrict__ ctx) {
  __shared__ float qs[D_];
  const int blk = blockIdx.x;               // 64 blocks
  const int b = blk >> 1, uh = (blk & 1) * 256;
  const int tid = threadIdx.x;              // 256
  qs[tid] = query[b * D_ + tid];
  qs[tid + 256] = query[b * D_ + tid + 256];
  __syncthreads();
  const int u = uh + tid;
  float a0 = 0, a1 = 0, a2 = 0, a3 = 0, a4 = 0, a5 = 0, a6 = 0, a7 = 0;
  for (int d = 0; d < D_; d += 8) {
    a0 += qs[d + 0] * W1[(size_t)(d + 0) * U_ + u];
    a1 += qs[d + 1] * W1[(size_t)(d + 1) * U_ + u];
    a2 += qs[d + 2] * W1[(size_t)(d + 2) * U_ + u];
    a3 += qs[d + 3] * W1[(size_t)(d + 3) * U_ + u];
    a4 += qs[d + 4] * W1[(size_t)(d + 4) * U_ + u];
    a5 += qs[d + 5] * W1[(size_t)(d + 5) * U_ + u];
    a6 += qs[d + 6] * W1[(size_t)(d + 6) * U_ + u];
    a7 += qs[d + 7] * W1[(size_t)(d + 7) * U_ + u];
  }
  qp[b * U_ + u] = ((a0 + a1) + (a2 + a3)) + ((a4 + a5) + (a6 + a7)) + W1b[u] + W2b[u];
  // zero init for atomics (ws and d_out are poisoned 0xAA each launch)
  const int gt = blk * 256 + tid;           // 0..16383
  ctx[gt] = 0.0f;
  #pragma unroll
  for (int i = 0; i < 4; ++i) score[i * 16384 + gt] = 0.0f;
}

// ---------- k2: score[m] = sum_u tanh(values@W2 + qp) * Vw  (bf16 MFMA) ----------
// 64-row m-tile; K split into two halves of 256; B fragments register-double-buffered
// across kk so the ~200-400cy L2 load latency overlaps the 32 MFMAs of the prior step.
__global__ __launch_bounds__(256, 2) void k2_score(
    const float* __restrict__ values, const unsigned short* __restrict__ W2T,
    const float* __restrict__ qp, const float* __restrict__ Vw,
    float* __restrict__ score) {
  constexpr int LS = 264;                   // 256 + 8 pad shorts; 528 B row (16B aligned)
  __shared__ unsigned short av[64 * LS];    // 33792 B; total static LDS ~37.9 KB
  __shared__ float qv[U_];
  __shared__ float vwv[U_];
  const int tid = threadIdx.x;
  const int m0 = blockIdx.x * 64;           // 1024 blocks (2048%64==0: tile never crosses batch)
  const int b = m0 >> 11;                   // T = 2048
  qv[tid] = qp[b * U_ + tid];        qv[tid + 256] = qp[b * U_ + tid + 256];
  vwv[tid] = Vw[tid];                vwv[tid + 256] = Vw[tid + 256];

  const int l = tid & 63, w = tid >> 6;     // wave id: u range [w*128, w*128+128)
  const int lr = l & 15, lq = l >> 4;

  f32x4 acc[4][8];                          // [mi][ni] -> 128 VGPRs
  #pragma unroll
  for (int mi = 0; mi < 4; ++mi)
    #pragma unroll
    for (int ni = 0; ni < 8; ++ni) acc[mi][ni] = (f32x4){0.f, 0.f, 0.f, 0.f};

  const unsigned short* wbase = W2T + (size_t)(w * 128 + lr) * D_ + lq * 8;
  const int abase = lr * LS + lq * 8;

  #pragma unroll
  for (int half = 0; half < 2; ++half) {
    // stage 64 rows x 256 d (fp32 -> bf16)
    const float4* vb = (const float4*)(values + (size_t)m0 * D_ + half * 256);
    #pragma unroll
    for (int it = 0; it < 16; ++it) {
      int i = tid + it * 256;               // 0..4095
      int row = i >> 6, c4 = i & 63;        // 64 float4 per row-half
      float4 v = vb[(size_t)row * 128 + c4];
      uint2 p; p.x = pack2bf(v.x, v.y); p.y = pack2bf(v.z, v.w);
      *(uint2*)&av[row * LS + c4 * 4] = p;
    }
    __syncthreads();
    const unsigned short* bh = wbase + half * 256;
    // register double-buffer for B fragments
    bf16x8 bcur[8], bnext[8];
    #pragma unroll
    for (int ni = 0; ni < 8; ++ni)
      bcur[ni] = *(const bf16x8*)(bh + (size_t)ni * 16 * D_);
    #pragma unroll
    for (int kk = 0; kk < 8; ++kk) {        // K-half = 256 = 8 x 32
      if (kk < 7) {
        #pragma unroll
        for (int ni = 0; ni < 8; ++ni)      // issue next-kk loads BEFORE current MFMAs
          bnext[ni] = *(const bf16x8*)(bh + (size_t)ni * 16 * D_ + (kk + 1) * 32);
      }
      bf16x8 a[4];
      #pragma unroll
      for (int mi = 0; mi < 4; ++mi)
        a[mi] = *(const bf16x8*)&av[abase + mi * 16 * LS + kk * 32];
      #pragma unroll
      for (int ni = 0; ni < 8; ++ni)
        #pragma unroll
        for (int mi = 0; mi < 4; ++mi)
          acc[mi][ni] = __builtin_amdgcn_mfma_f32_16x16x32_bf16(a[mi], bcur[ni], acc[mi][ni], 0, 0, 0);
      if (kk < 7) {
        #pragma unroll
        for (int ni = 0; ni < 8; ++ni) bcur[ni] = bnext[ni];
      }
    }
    __syncthreads();                        // protect av before restage
  }

  // epilogue: tanh + weighted reduce over u (C/D: col=lane&15 -> u, row=lq*4+reg -> m)
  float sacc[4][4];
  #pragma unroll
  for (int mi = 0; mi < 4; ++mi)
    #pragma unroll
    for (int r = 0; r < 4; ++r) sacc[mi][r] = 0.0f;
  #pragma unroll
  for (int ni = 0; ni < 8; ++ni) {
    int u = w * 128 + ni * 16 + lr;
    float qpv = qv[u], vv = vwv[u];
    #pragma unroll
    for (int mi = 0; mi < 4; ++mi)
      #pragma unroll
      for (int r = 0; r < 4; ++r)
        sacc[mi][r] += tanh_fast(acc[mi][ni][r] + qpv) * vv;
  }
  // reduce 16 lanes (u within tile), then one atomic per row per wave
  #pragma unroll
  for (int mi = 0; mi < 4; ++mi)
    #pragma unroll
    for (int r = 0; r < 4; ++r) {
      float v = sacc[mi][r];
      v += __shfl_xor(v, 1); v += __shfl_xor(v, 2);
      v += __shfl_xor(v, 4); v += __shfl_xor(v, 8);
      if (lr == 0) atomicAdd(&score[m0 + mi * 16 + lq * 4 + r], v);
    }
}

// ---------- k3: softmax over T per batch (in-place: score region == attn region) ----------
__global__ void k3_softmax(const float* __restrict__ score, float* __restrict__ attn) {
  __shared__ float red[8];
  const int b = blockIdx.x, tid = threadIdx.x;  // 32 blocks x 256
  const float* s = score + b * T_;
  float v[8];
  float mx = -1e30f;
  #pragma unroll
  for (int i = 0; i < 8; ++i) { v[i] = s[tid + i * 256]; mx = fmaxf(mx, v[i]); }
  #pragma unroll
  for (int off = 1; off < 64; off <<= 1) mx = fmaxf(mx, __shfl_xor(mx, off));
  if ((tid & 63) == 0) red[tid >> 6] = mx;
  __syncthreads();
  mx = fmaxf(fmaxf(red[0], red[1]), fmaxf(red[2], red[3]));
  float sum = 0.0f;
  #pragma unroll
  for (int i = 0; i < 8; ++i) { v[i] = __expf(v[i] - mx); sum += v[i]; }
  #pragma unroll
  for (int off = 1; off < 64; off <<= 1) sum += __shfl_xor(sum, off);
  if ((tid & 63) == 0) red[4 + (tid >> 6)] = sum;
  __syncthreads();
  sum = (red[4] + red[5]) + (red[6] + red[7]);
  float inv = 1.0f / sum;
  // safe in-place: each thread writes only positions it alone read
  #pragma unroll
  for (int i = 0; i < 8; ++i) attn[b * T_ + tid + i * 256] = v[i] * inv;
}

// ---------- k4: context[b,:] = sum_t attn[b,t] * values[b,t,:] ----------
// 1024 blocks (32 b x 32 t-chunks of 64 rows); float4 loads; LDS pair-reduce + atomics.
__global__ void k4_ctx(const float* __restrict__ values, const float* __restrict__ attn,
                       float* __restrict__ ctx) {
  __shared__ float at[64];
  __shared__ float ps[512];
  const int blk = blockIdx.x;
  const int b = blk >> 5, tc = blk & 31;
  const int tid = threadIdx.x;              // 256
  if (tid < 64) at[tid] = attn[b * T_ + tc * 64 + tid];
  __syncthreads();
  const int q = tid & 127;                  // float4 index within row (covers 512 floats)
  const int r0 = tid >> 7;                  // row parity 0/1
  const float4* vb = (const float4*)(values + ((size_t)b * T_ + tc * 64) * D_);
  float ax = 0.f, ay = 0.f, az = 0.f, aw = 0.f;
  #pragma unroll 8
  for (int tt = 0; tt < 32; ++tt) {
    int row = tt * 2 + r0;
    float4 v = vb[(size_t)row * 128 + q];   // 64 lanes x 16B = one full 2KB row per wave-pair
    float a = at[row];
    ax += a * v.x; ay += a * v.y; az += a * v.z; aw += a * v.w;
  }
  if (r0 == 1) { ps[4 * q] = ax; ps[4 * q + 1] = ay; ps[4 * q + 2] = az; ps[4 * q + 3] = aw; }
  __syncthreads();
  if (r0 == 0) {
    atomicAdd(&ctx[b * D_ + 4 * q + 0], ax + ps[4 * q + 0]);
    atomicAdd(&ctx[b * D_ + 4 * q + 1], ay + ps[4 * q + 1]);
    atomicAdd(&ctx[b * D_ + 4 * q + 2], az + ps[4 * q + 2]);
    atomicAdd(&ctx[b * D_ + 4 * q + 3], aw + ps[4 * q + 3]);
  }
}

extern "C" void kernel_launch(void* const* d_in, const int* in_sizes, int n_in,
                              void* d_out, int out_size, void* d_ws, size_t ws_size,
                              hipStream_t stream) {
  const float* query = (const float*)d_in[0];
  const float* values = (const float*)d_in[1];
  const float* W1w = (const float*)d_in[2];
  const float* W1b = (const float*)d_in[3];
  const float* W2w = (const float*)d_in[4];
  const float* W2b = (const float*)d_in[5];
  const float* Vw  = (const float*)d_in[6];
  // V_b (d_in[7]) is a constant shift under softmax -> attn/context invariant; dropped.

  float* out = (float*)d_out;
  float* ctx  = out;                 // [B, D]    = 16384 floats
  float* attn = out + B_ * D_;       // [B, T, 1] = 65536 floats
  float* score = attn;               // raw scores share the attn region; k3 softmaxes in place

  char* ws = (char*)d_ws;            // needs 576 KB
  unsigned short* W2T = (unsigned short*)ws;                 // 512 KB bf16 [U][D]
  float* qp    = (float*)(ws + 512 * 1024);                  // 64 KB

  k0_w2t<<<dim3(8, 16), 256, 0, stream>>>(W2w, W2T);
  k1_qp<<<64, 256, 0, stream>>>(query, W1w, W1b, W2b, qp, score, ctx);
  k2_score<<<1024, 256, 0, stream>>>(values, W2T, qp, Vw, score);
  k3_softmax<<<32, 256, 0, stream>>>(score, attn);
  k4_ctx<<<1024, 256, 0, stream>>>(values, attn, ctx);
}

// Round 5
// 298.289 us; speedup vs baseline: 1.0720x; 1.0720x over previous
//
#include <hip/hip_runtime.h>
#include <hip/hip_bf16.h>
#include <cstddef>

#define B_ 32
#define T_ 2048
#define D_ 512
#define U_ 512

typedef __attribute__((ext_vector_type(8))) short bf16x8;   // 8 bf16 = 4 VGPRs
typedef __attribute__((ext_vector_type(4))) float f32x4;    // MFMA 16x16 accum

__device__ __forceinline__ unsigned short f2bf(float f) {
  union { float f; unsigned u; } x; x.f = f;
  unsigned r = x.u + 0x7fffu + ((x.u >> 16) & 1u);  // RNE
  return (unsigned short)(r >> 16);
}
__device__ __forceinline__ unsigned pack2bf(float a, float b) {
  return (unsigned)f2bf(a) | ((unsigned)f2bf(b) << 16);
}
__device__ __forceinline__ float tanh_fast(float x) {
  // tanh(x) = 1 - 2/(e^{2x}+1); saturates correctly at +/-inf
  float e = __expf(2.0f * x);
  return 1.0f - 2.0f * __builtin_amdgcn_rcpf(e + 1.0f);
}

// ---------- k0: W2 [D][U] fp32 -> W2P bf16 packed in MFMA B-fragment order ----------
// Tile t = ut*16 + kk (ut: u-tile of 16, kk: k-step of 32) is 1KB: lane l holds
// 8 shorts = W2T[ut*16 + (l&15)][kk*32 + (l>>4)*8 + j]  (j=0..7, consecutive k).
// k2's per-(ni,kk) wave load becomes one contiguous 1KB segment (base + l*16B).
__global__ void k0_pack(const float* __restrict__ W2, unsigned* __restrict__ W2P) {
  const int tid = threadIdx.x;              // 256 blocks x 256 threads x 2 uints
  #pragma unroll
  for (int ii = 0; ii < 2; ++ii) {
    int p = blockIdx.x * 512 + ii * 256 + tid;   // uint index 0..131071
    int j = (p & 3) * 2;
    int l = (p >> 2) & 63;
    int t = p >> 8;
    int u = (t >> 4) * 16 + (l & 15);
    int k = (t & 15) * 32 + ((l >> 4) << 3) + j;
    float f0 = W2[(size_t)k * U_ + u];
    float f1 = W2[(size_t)(k + 1) * U_ + u];
    W2P[p] = pack2bf(f0, f1);
  }
}

// ---------- k1: q_proj (+ fold W1_b + W2_b) ; zero score & context ----------
__global__ void k1_qp(const float* __restrict__ query, const float* __restrict__ W1,
                      const float* __restrict__ W1b, const float* __restrict__ W2b,
                      float* __restrict__ qp, float* __restrict__ score,
                      float* __restrict__ ctx) {
  __shared__ float qs[D_];
  const int blk = blockIdx.x;               // 64 blocks
  const int b = blk >> 1, uh = (blk & 1) * 256;
  const int tid = threadIdx.x;              // 256
  qs[tid] = query[b * D_ + tid];
  qs[tid + 256] = query[b * D_ + tid + 256];
  __syncthreads();
  const int u = uh + tid;
  float a0 = 0, a1 = 0, a2 = 0, a3 = 0, a4 = 0, a5 = 0, a6 = 0, a7 = 0;
  for (int d = 0; d < D_; d += 8) {
    a0 += qs[d + 0] * W1[(size_t)(d + 0) * U_ + u];
    a1 += qs[d + 1] * W1[(size_t)(d + 1) * U_ + u];
    a2 += qs[d + 2] * W1[(size_t)(d + 2) * U_ + u];
    a3 += qs[d + 3] * W1[(size_t)(d + 3) * U_ + u];
    a4 += qs[d + 4] * W1[(size_t)(d + 4) * U_ + u];
    a5 += qs[d + 5] * W1[(size_t)(d + 5) * U_ + u];
    a6 += qs[d + 6] * W1[(size_t)(d + 6) * U_ + u];
    a7 += qs[d + 7] * W1[(size_t)(d + 7) * U_ + u];
  }
  qp[b * U_ + u] = ((a0 + a1) + (a2 + a3)) + ((a4 + a5) + (a6 + a7)) + W1b[u] + W2b[u];
  // zero init for atomics (ws and d_out are poisoned 0xAA each launch)
  const int gt = blk * 256 + tid;           // 0..16383
  ctx[gt] = 0.0f;
  #pragma unroll
  for (int i = 0; i < 4; ++i) score[i * 16384 + gt] = 0.0f;
}

// ---------- k2: score[m] = sum_u tanh(values@W2 + qp) * Vw  (bf16 MFMA) ----------
// 64-row m-tile; K in two halves of 256 (LDS < 64KiB). B from packed W2P:
// one coalesced 1KB load per (ni,kk) fragment, ping-pong double-buffered over kk.
__global__ __launch_bounds__(256, 2) void k2_score(
    const float* __restrict__ values, const unsigned short* __restrict__ W2P,
    const float* __restrict__ qp, const float* __restrict__ Vw,
    float* __restrict__ score) {
  constexpr int LS = 264;                   // 256 + 8 pad shorts; 528 B row (16B aligned)
  __shared__ unsigned short av[64 * LS];    // 33792 B; total static LDS ~37.9 KB
  __shared__ float qv[U_];
  __shared__ float vwv[U_];
  const int tid = threadIdx.x;
  const int m0 = blockIdx.x * 64;           // 1024 blocks (2048%64==0: tile never crosses batch)
  const int b = m0 >> 11;                   // T = 2048
  qv[tid] = qp[b * U_ + tid];        qv[tid + 256] = qp[b * U_ + tid + 256];
  vwv[tid] = Vw[tid];                vwv[tid + 256] = Vw[tid + 256];

  const int l = tid & 63, w = tid >> 6;     // wave id: u range [w*128, w*128+128)
  const int lr = l & 15, lq = l >> 4;

  f32x4 acc[4][8];                          // [mi][ni] -> 128 AGPRs
  #pragma unroll
  for (int mi = 0; mi < 4; ++mi)
    #pragma unroll
    for (int ni = 0; ni < 8; ++ni) acc[mi][ni] = (f32x4){0.f, 0.f, 0.f, 0.f};

  // packed-B wave base: ut = w*8 + ni, tile = ut*16 + kkg; short offset = tile*512 + l*8
  const unsigned short* bw = W2P + (size_t)(w * 8) * 8192 + (size_t)l * 8;
  const int abase = lr * LS + lq * 8;

  #pragma unroll
  for (int half = 0; half < 2; ++half) {
    // stage 64 rows x 256 d (fp32 -> bf16)
    const float4* vb = (const float4*)(values + (size_t)m0 * D_ + half * 256);
    #pragma unroll
    for (int it = 0; it < 16; ++it) {
      int i = tid + it * 256;               // 0..4095
      int row = i >> 6, c4 = i & 63;        // 64 float4 per row-half
      float4 v = vb[(size_t)row * 128 + c4];
      uint2 p; p.x = pack2bf(v.x, v.y); p.y = pack2bf(v.z, v.w);
      *(uint2*)&av[row * LS + c4 * 4] = p;
    }
    __syncthreads();
    const int kg0 = half * 8;
    bf16x8 b0[8], b1[8];
    #pragma unroll
    for (int ni = 0; ni < 8; ++ni)
      b0[ni] = *(const bf16x8*)(bw + (size_t)ni * 8192 + (size_t)kg0 * 512);
    #pragma unroll
    for (int kk = 0; kk < 8; ++kk) {        // K-half = 256 = 8 x 32
      bf16x8* cur = (kk & 1) ? b1 : b0;
      bf16x8* nxt = (kk & 1) ? b0 : b1;
      if (kk < 7) {
        #pragma unroll
        for (int ni = 0; ni < 8; ++ni)      // issue next-kk loads BEFORE current MFMAs
          nxt[ni] = *(const bf16x8*)(bw + (size_t)ni * 8192 + (size_t)(kg0 + kk + 1) * 512);
      }
      bf16x8 a[4];
      #pragma unroll
      for (int mi = 0; mi < 4; ++mi)
        a[mi] = *(const bf16x8*)&av[abase + mi * 16 * LS + kk * 32];
      #pragma unroll
      for (int ni = 0; ni < 8; ++ni)
        #pragma unroll
        for (int mi = 0; mi < 4; ++mi)
          acc[mi][ni] = __builtin_amdgcn_mfma_f32_16x16x32_bf16(a[mi], cur[ni], acc[mi][ni], 0, 0, 0);
    }
    __syncthreads();                        // protect av before restage
  }

  // epilogue: tanh + weighted reduce over u (C/D: col=lane&15 -> u, row=lq*4+reg -> m)
  float sacc[4][4];
  #pragma unroll
  for (int mi = 0; mi < 4; ++mi)
    #pragma unroll
    for (int r = 0; r < 4; ++r) sacc[mi][r] = 0.0f;
  #pragma unroll
  for (int ni = 0; ni < 8; ++ni) {
    int u = w * 128 + ni * 16 + lr;
    float qpv = qv[u], vv = vwv[u];
    #pragma unroll
    for (int mi = 0; mi < 4; ++mi)
      #pragma unroll
      for (int r = 0; r < 4; ++r)
        sacc[mi][r] += tanh_fast(acc[mi][ni][r] + qpv) * vv;
  }
  // reduce 16 lanes (u within tile), then one atomic per row per wave
  #pragma unroll
  for (int mi = 0; mi < 4; ++mi)
    #pragma unroll
    for (int r = 0; r < 4; ++r) {
      float v = sacc[mi][r];
      v += __shfl_xor(v, 1); v += __shfl_xor(v, 2);
      v += __shfl_xor(v, 4); v += __shfl_xor(v, 8);
      if (lr == 0) atomicAdd(&score[m0 + mi * 16 + lq * 4 + r], v);
    }
}

// ---------- k3: softmax over T per batch (in-place: score region == attn region) ----------
__global__ void k3_softmax(const float* __restrict__ score, float* __restrict__ attn) {
  __shared__ float red[8];
  const int b = blockIdx.x, tid = threadIdx.x;  // 32 blocks x 256
  const float* s = score + b * T_;
  float v[8];
  float mx = -1e30f;
  #pragma unroll
  for (int i = 0; i < 8; ++i) { v[i] = s[tid + i * 256]; mx = fmaxf(mx, v[i]); }
  #pragma unroll
  for (int off = 1; off < 64; off <<= 1) mx = fmaxf(mx, __shfl_xor(mx, off));
  if ((tid & 63) == 0) red[tid >> 6] = mx;
  __syncthreads();
  mx = fmaxf(fmaxf(red[0], red[1]), fmaxf(red[2], red[3]));
  float sum = 0.0f;
  #pragma unroll
  for (int i = 0; i < 8; ++i) { v[i] = __expf(v[i] - mx); sum += v[i]; }
  #pragma unroll
  for (int off = 1; off < 64; off <<= 1) sum += __shfl_xor(sum, off);
  if ((tid & 63) == 0) red[4 + (tid >> 6)] = sum;
  __syncthreads();
  sum = (red[4] + red[5]) + (red[6] + red[7]);
  float inv = 1.0f / sum;
  // safe in-place: each thread writes only positions it alone read
  #pragma unroll
  for (int i = 0; i < 8; ++i) attn[b * T_ + tid + i * 256] = v[i] * inv;
}

// ---------- k4: context[b,:] = sum_t attn[b,t] * values[b,t,:] ----------
// 1024 blocks (32 b x 32 t-chunks of 64 rows); float4 loads; LDS pair-reduce + atomics.
__global__ void k4_ctx(const float* __restrict__ values, const float* __restrict__ attn,
                       float* __restrict__ ctx) {
  __shared__ float at[64];
  __shared__ float ps[512];
  const int blk = blockIdx.x;
  const int b = blk >> 5, tc = blk & 31;
  const int tid = threadIdx.x;              // 256
  if (tid < 64) at[tid] = attn[b * T_ + tc * 64 + tid];
  __syncthreads();
  const int q = tid & 127;                  // float4 index within row (covers 512 floats)
  const int r0 = tid >> 7;                  // row parity 0/1
  const float4* vb = (const float4*)(values + ((size_t)b * T_ + tc * 64) * D_);
  float ax = 0.f, ay = 0.f, az = 0.f, aw = 0.f;
  #pragma unroll 8
  for (int tt = 0; tt < 32; ++tt) {
    int row = tt * 2 + r0;
    float4 v = vb[(size_t)row * 128 + q];   // 64 lanes x 16B = one full 2KB row per wave-pair
    float a = at[row];
    ax += a * v.x; ay += a * v.y; az += a * v.z; aw += a * v.w;
  }
  if (r0 == 1) { ps[4 * q] = ax; ps[4 * q + 1] = ay; ps[4 * q + 2] = az; ps[4 * q + 3] = aw; }
  __syncthreads();
  if (r0 == 0) {
    atomicAdd(&ctx[b * D_ + 4 * q + 0], ax + ps[4 * q + 0]);
    atomicAdd(&ctx[b * D_ + 4 * q + 1], ay + ps[4 * q + 1]);
    atomicAdd(&ctx[b * D_ + 4 * q + 2], az + ps[4 * q + 2]);
    atomicAdd(&ctx[b * D_ + 4 * q + 3], aw + ps[4 * q + 3]);
  }
}

extern "C" void kernel_launch(void* const* d_in, const int* in_sizes, int n_in,
                              void* d_out, int out_size, void* d_ws, size_t ws_size,
                              hipStream_t stream) {
  const float* query = (const float*)d_in[0];
  const float* values = (const float*)d_in[1];
  const float* W1w = (const float*)d_in[2];
  const float* W1b = (const float*)d_in[3];
  const float* W2w = (const float*)d_in[4];
  const float* W2b = (const float*)d_in[5];
  const float* Vw  = (const float*)d_in[6];
  // V_b (d_in[7]) is a constant shift under softmax -> attn/context invariant; dropped.

  float* out = (float*)d_out;
  float* ctx  = out;                 // [B, D]    = 16384 floats
  float* attn = out + B_ * D_;       // [B, T, 1] = 65536 floats
  float* score = attn;               // raw scores share the attn region; k3 softmaxes in place

  char* ws = (char*)d_ws;            // needs 576 KB
  unsigned* W2P = (unsigned*)ws;                             // 512 KB bf16 packed fragments
  float* qp    = (float*)(ws + 512 * 1024);                  // 64 KB

  k0_pack<<<256, 256, 0, stream>>>(W2w, W2P);
  k1_qp<<<64, 256, 0, stream>>>(query, W1w, W1b, W2b, qp, score, ctx);
  k2_score<<<1024, 256, 0, stream>>>(values, (const unsigned short*)W2P, qp, Vw, score);
  k3_softmax<<<32, 256, 0, stream>>>(score, attn);
  k4_ctx<<<1024, 256, 0, stream>>>(values, attn, ctx);
}

// Round 6
// 296.763 us; speedup vs baseline: 1.0775x; 1.0051x over previous
//
#include <hip/hip_runtime.h>
#include <hip/hip_bf16.h>
#include <cstddef>

#define B_ 32
#define T_ 2048
#define D_ 512
#define U_ 512

typedef __attribute__((ext_vector_type(8))) short bf16x8;   // 8 bf16 = 4 VGPRs
typedef __attribute__((ext_vector_type(4))) float f32x4;    // MFMA 16x16 accum

__device__ __forceinline__ unsigned short f2bf(float f) {
  union { float f; unsigned u; } x; x.f = f;
  unsigned r = x.u + 0x7fffu + ((x.u >> 16) & 1u);  // RNE
  return (unsigned short)(r >> 16);
}
__device__ __forceinline__ unsigned pack2bf(float a, float b) {
  return (unsigned)f2bf(a) | ((unsigned)f2bf(b) << 16);
}
__device__ __forceinline__ float tanh_fast(float x) {
  float e = __expf(2.0f * x);
  return 1.0f - 2.0f * __builtin_amdgcn_rcpf(e + 1.0f);
}

// ---------- kA: fused W2 pack (blocks 0..255) + q_proj/zero-init (blocks 256..319) ----------
// Pack: tile t = ut*16 + kk is 1KB: lane l holds 8 shorts =
// W2T[ut*16 + (l&15)][kk*32 + (l>>4)*8 + j], so k2's B-load is base + l*16B (coalesced).
__global__ void kA_prep(const float* __restrict__ W2, unsigned* __restrict__ W2P,
                        const float* __restrict__ query, const float* __restrict__ W1,
                        const float* __restrict__ W1b, const float* __restrict__ W2b,
                        float* __restrict__ qp, float* __restrict__ score,
                        float* __restrict__ ctx) {
  const int tid = threadIdx.x;              // 256
  if (blockIdx.x < 256) {
    #pragma unroll
    for (int ii = 0; ii < 2; ++ii) {
      int p = blockIdx.x * 512 + ii * 256 + tid;   // uint index 0..131071
      int j = (p & 3) * 2;
      int l = (p >> 2) & 63;
      int t = p >> 8;
      int u = (t >> 4) * 16 + (l & 15);
      int k = (t & 15) * 32 + ((l >> 4) << 3) + j;
      W2P[p] = pack2bf(W2[(size_t)k * U_ + u], W2[(size_t)(k + 1) * U_ + u]);
    }
  } else {
    __shared__ float qs[D_];
    const int blk = blockIdx.x - 256;       // 0..63
    const int b = blk >> 1, uhh = (blk & 1) * 256;
    qs[tid] = query[b * D_ + tid];
    qs[tid + 256] = query[b * D_ + tid + 256];
    __syncthreads();
    const int u = uhh + tid;
    float a0 = 0, a1 = 0, a2 = 0, a3 = 0, a4 = 0, a5 = 0, a6 = 0, a7 = 0;
    for (int d = 0; d < D_; d += 8) {
      a0 += qs[d + 0] * W1[(size_t)(d + 0) * U_ + u];
      a1 += qs[d + 1] * W1[(size_t)(d + 1) * U_ + u];
      a2 += qs[d + 2] * W1[(size_t)(d + 2) * U_ + u];
      a3 += qs[d + 3] * W1[(size_t)(d + 3) * U_ + u];
      a4 += qs[d + 4] * W1[(size_t)(d + 4) * U_ + u];
      a5 += qs[d + 5] * W1[(size_t)(d + 5) * U_ + u];
      a6 += qs[d + 6] * W1[(size_t)(d + 6) * U_ + u];
      a7 += qs[d + 7] * W1[(size_t)(d + 7) * U_ + u];
    }
    qp[b * U_ + u] = ((a0 + a1) + (a2 + a3)) + ((a4 + a5) + (a6 + a7)) + W1b[u] + W2b[u];
    // zero init for atomics (d_out/d_ws re-poisoned 0xAA before every launch)
    const int gt = blk * 256 + tid;         // 0..16383
    ctx[gt] = 0.0f;
    #pragma unroll
    for (int i = 0; i < 4; ++i) score[i * 16384 + gt] = 0.0f;
  }
}

// ---------- k2: score[m] += sum_u tanh(values@W2 + qp) * Vw  (bf16 MFMA) ----------
// Grid 2048: block = (m-tile of 64) x (u-half of 256). Wave = 4m x 4u tiles ->
// acc[4][4] = 64 AGPRs, ~160 regs/wave -> 3 blocks/CU (12 waves) for TLP latency hiding.
__global__ __launch_bounds__(256, 3) void k2_score(
    const float* __restrict__ values, const unsigned short* __restrict__ W2P,
    const float* __restrict__ qp, const float* __restrict__ Vw,
    float* __restrict__ score) {
  constexpr int LS = 264;                   // 256 + 8 pad shorts; 528 B row (16B aligned)
  __shared__ unsigned short av[64 * LS];    // 33792 B
  __shared__ float qv[256];
  __shared__ float vwv[256];
  const int tid = threadIdx.x;
  const int bx = blockIdx.x;
  const int mt = bx >> 1, uh = bx & 1;      // consecutive blocks share the A-tile (L2/L3 reuse)
  const int m0 = mt * 64;                   // 2048%64==0: tile never crosses batch
  const int b = m0 >> 11;
  const int ub = uh * 256;
  qv[tid] = qp[b * U_ + ub + tid];
  vwv[tid] = Vw[ub + tid];

  const int l = tid & 63, w = tid >> 6;     // wave w owns u_local [w*64, w*64+64)
  const int lr = l & 15, lq = l >> 4;

  f32x4 acc[4][4];                          // [mi][ni] -> 64 AGPRs
  #pragma unroll
  for (int mi = 0; mi < 4; ++mi)
    #pragma unroll
    for (int ni = 0; ni < 4; ++ni) acc[mi][ni] = (f32x4){0.f, 0.f, 0.f, 0.f};

  // packed-B: global u-tile = uh*16 + w*4 + ni; short offset = ut*8192 + kg*512 + l*8
  const unsigned short* bw = W2P + (size_t)(uh * 16 + w * 4) * 8192 + (size_t)l * 8;
  const int abase = lr * LS + lq * 8;

  #pragma unroll
  for (int half = 0; half < 2; ++half) {
    // stage 64 rows x 256 d (fp32 -> bf16)
    const float4* vb = (const float4*)(values + (size_t)m0 * D_ + half * 256);
    #pragma unroll
    for (int it = 0; it < 16; ++it) {
      int i = tid + it * 256;               // 0..4095
      int row = i >> 6, c4 = i & 63;
      float4 v = vb[(size_t)row * 128 + c4];
      uint2 p; p.x = pack2bf(v.x, v.y); p.y = pack2bf(v.z, v.w);
      *(uint2*)&av[row * LS + c4 * 4] = p;
    }
    __syncthreads();
    const int kg0 = half * 8;
    bf16x8 b0[4], b1[4];
    #pragma unroll
    for (int ni = 0; ni < 4; ++ni)
      b0[ni] = *(const bf16x8*)(bw + (size_t)ni * 8192 + (size_t)kg0 * 512);
    #pragma unroll
    for (int kk = 0; kk < 8; ++kk) {        // K-half = 256 = 8 x 32
      bf16x8* cur = (kk & 1) ? b1 : b0;
      bf16x8* nxt = (kk & 1) ? b0 : b1;
      if (kk < 7) {
        #pragma unroll
        for (int ni = 0; ni < 4; ++ni)      // prefetch next kk before current MFMAs
          nxt[ni] = *(const bf16x8*)(bw + (size_t)ni * 8192 + (size_t)(kg0 + kk + 1) * 512);
      }
      bf16x8 a[4];
      #pragma unroll
      for (int mi = 0; mi < 4; ++mi)
        a[mi] = *(const bf16x8*)&av[abase + mi * 16 * LS + kk * 32];
      #pragma unroll
      for (int ni = 0; ni < 4; ++ni)
        #pragma unroll
        for (int mi = 0; mi < 4; ++mi)
          acc[mi][ni] = __builtin_amdgcn_mfma_f32_16x16x32_bf16(a[mi], cur[ni], acc[mi][ni], 0, 0, 0);
    }
    __syncthreads();                        // protect av before restage
  }

  // epilogue: tanh + weighted reduce over u (C/D: col=lane&15 -> u, row=lq*4+reg -> m)
  float sacc[4][4];
  #pragma unroll
  for (int mi = 0; mi < 4; ++mi)
    #pragma unroll
    for (int r = 0; r < 4; ++r) sacc[mi][r] = 0.0f;
  #pragma unroll
  for (int ni = 0; ni < 4; ++ni) {
    int ul = w * 64 + ni * 16 + lr;
    float qpv = qv[ul], vv = vwv[ul];
    #pragma unroll
    for (int mi = 0; mi < 4; ++mi)
      #pragma unroll
      for (int r = 0; r < 4; ++r)
        sacc[mi][r] += tanh_fast(acc[mi][ni][r] + qpv) * vv;
  }
  #pragma unroll
  for (int mi = 0; mi < 4; ++mi)
    #pragma unroll
    for (int r = 0; r < 4; ++r) {
      float v = sacc[mi][r];
      v += __shfl_xor(v, 1); v += __shfl_xor(v, 2);
      v += __shfl_xor(v, 4); v += __shfl_xor(v, 8);
      if (lr == 0) atomicAdd(&score[m0 + mi * 16 + lq * 4 + r], v);
    }
}

// ---------- k3: softmax over T per batch (in-place: score region == attn region) ----------
__global__ void k3_softmax(const float* __restrict__ score, float* __restrict__ attn) {
  __shared__ float red[8];
  const int b = blockIdx.x, tid = threadIdx.x;  // 32 blocks x 256
  const float* s = score + b * T_;
  float v[8];
  float mx = -1e30f;
  #pragma unroll
  for (int i = 0; i < 8; ++i) { v[i] = s[tid + i * 256]; mx = fmaxf(mx, v[i]); }
  #pragma unroll
  for (int off = 1; off < 64; off <<= 1) mx = fmaxf(mx, __shfl_xor(mx, off));
  if ((tid & 63) == 0) red[tid >> 6] = mx;
  __syncthreads();
  mx = fmaxf(fmaxf(red[0], red[1]), fmaxf(red[2], red[3]));
  float sum = 0.0f;
  #pragma unroll
  for (int i = 0; i < 8; ++i) { v[i] = __expf(v[i] - mx); sum += v[i]; }
  #pragma unroll
  for (int off = 1; off < 64; off <<= 1) sum += __shfl_xor(sum, off);
  if ((tid & 63) == 0) red[4 + (tid >> 6)] = sum;
  __syncthreads();
  sum = (red[4] + red[5]) + (red[6] + red[7]);
  float inv = 1.0f / sum;
  #pragma unroll
  for (int i = 0; i < 8; ++i) attn[b * T_ + tid + i * 256] = v[i] * inv;
}

// ---------- k4: context[b,:] = sum_t attn[b,t] * values[b,t,:] ----------
__global__ void k4_ctx(const float* __restrict__ values, const float* __restrict__ attn,
                       float* __restrict__ ctx) {
  __shared__ float at[64];
  __shared__ float ps[512];
  const int blk = blockIdx.x;               // 1024 = 32 b x 32 t-chunks of 64
  const int b = blk >> 5, tc = blk & 31;
  const int tid = threadIdx.x;              // 256
  if (tid < 64) at[tid] = attn[b * T_ + tc * 64 + tid];
  __syncthreads();
  const int q = tid & 127;
  const int r0 = tid >> 7;
  const float4* vb = (const float4*)(values + ((size_t)b * T_ + tc * 64) * D_);
  float ax = 0.f, ay = 0.f, az = 0.f, aw = 0.f;
  #pragma unroll 8
  for (int tt = 0; tt < 32; ++tt) {
    int row = tt * 2 + r0;
    float4 v = vb[(size_t)row * 128 + q];
    float a = at[row];
    ax += a * v.x; ay += a * v.y; az += a * v.z; aw += a * v.w;
  }
  if (r0 == 1) { ps[4 * q] = ax; ps[4 * q + 1] = ay; ps[4 * q + 2] = az; ps[4 * q + 3] = aw; }
  __syncthreads();
  if (r0 == 0) {
    atomicAdd(&ctx[b * D_ + 4 * q + 0], ax + ps[4 * q + 0]);
    atomicAdd(&ctx[b * D_ + 4 * q + 1], ay + ps[4 * q + 1]);
    atomicAdd(&ctx[b * D_ + 4 * q + 2], az + ps[4 * q + 2]);
    atomicAdd(&ctx[b * D_ + 4 * q + 3], aw + ps[4 * q + 3]);
  }
}

extern "C" void kernel_launch(void* const* d_in, const int* in_sizes, int n_in,
                              void* d_out, int out_size, void* d_ws, size_t ws_size,
                              hipStream_t stream) {
  const float* query = (const float*)d_in[0];
  const float* values = (const float*)d_in[1];
  const float* W1w = (const float*)d_in[2];
  const float* W1b = (const float*)d_in[3];
  const float* W2w = (const float*)d_in[4];
  const float* W2b = (const float*)d_in[5];
  const float* Vw  = (const float*)d_in[6];
  // V_b (d_in[7]) is a constant shift under softmax -> attn/context invariant; dropped.

  float* out = (float*)d_out;
  float* ctx  = out;                 // [B, D]    = 16384 floats
  float* attn = out + B_ * D_;       // [B, T, 1] = 65536 floats
  float* score = attn;               // raw scores share the attn region; k3 softmaxes in place

  char* ws = (char*)d_ws;            // needs 576 KB
  unsigned* W2P = (unsigned*)ws;                             // 512 KB bf16 packed fragments
  float* qp    = (float*)(ws + 512 * 1024);                  // 64 KB

  kA_prep<<<320, 256, 0, stream>>>(W2w, W2P, query, W1w, W1b, W2b, qp, score, ctx);
  k2_score<<<2048, 256, 0, stream>>>(values, (const unsigned short*)W2P, qp, Vw, score);
  k3_softmax<<<32, 256, 0, stream>>>(score, attn);
  k4_ctx<<<1024, 256, 0, stream>>>(values, attn, ctx);
}